// Round 1
// baseline (4381.016 us; speedup 1.0000x reference)
//
#include <hip/hip_runtime.h>

#define N_NODES_C 50000
#define N_EDGES_C 640000
#define HD 128

typedef float f32x4 __attribute__((ext_vector_type(4)));
typedef short short8 __attribute__((ext_vector_type(8)));

// d_out layout (floats): [node_out 6.4M][edge_index 1.28M][edge_out 81.92M]
#define OUT_NODE 0
#define OUT_IDX  6400000
#define OUT_EDGE 7680000

// workspace layout (shorts = bf16), transposed weights [n][k]
#define EW0T 0        // 128x384
#define EW1T 49152    // 128x128
#define EW2T 65536
#define EW3T 81920
#define NW0T 98304    // 128x256
#define NW1T 131072
#define NW2T 147456
#define NW3T 163840
#define WTOT 180224

__device__ inline short f2bf(float f) {
  unsigned u = __builtin_bit_cast(unsigned, f);
  u += 0x7fffu + ((u >> 16) & 1u);   // RNE
  return (short)(u >> 16);
}

// ---------------- prep: zero agg, cast edge_index->float, transpose+cast weights ----------------
__global__ void prep_kernel(const float* __restrict__ ew0, const float* __restrict__ ew1,
                            const float* __restrict__ ew2, const float* __restrict__ ew3,
                            const float* __restrict__ nw0, const float* __restrict__ nw1,
                            const float* __restrict__ nw2, const float* __restrict__ nw3,
                            const int* __restrict__ eidx,
                            float* __restrict__ out, short* __restrict__ wbuf)
{
  const int total = 6400000 + 1280000 + WTOT;
  for (int i = blockIdx.x * blockDim.x + threadIdx.x; i < total; i += gridDim.x * blockDim.x) {
    if (i < 6400000) {
      out[OUT_NODE + i] = 0.f;                     // agg accumulator
    } else if (i < 7680000) {
      int j = i - 6400000;
      out[OUT_IDX + j] = (float)eidx[j];           // edge_index pass-through
    } else {
      int j = i - 7680000;
      short v;
      if (j < EW1T)      { int n = j / 384,  k = j - n * 384; v = f2bf(ew0[k * HD + n]); }
      else if (j < EW2T) { int t2 = j - EW1T, n = t2 >> 7, k = t2 & 127; v = f2bf(ew1[k * HD + n]); }
      else if (j < EW3T) { int t2 = j - EW2T, n = t2 >> 7, k = t2 & 127; v = f2bf(ew2[k * HD + n]); }
      else if (j < NW0T) { int t2 = j - EW3T, n = t2 >> 7, k = t2 & 127; v = f2bf(ew3[k * HD + n]); }
      else if (j < NW1T) { int t2 = j - NW0T, n = t2 >> 8, k = t2 & 255; v = f2bf(nw0[k * HD + n]); }
      else if (j < NW2T) { int t2 = j - NW1T, n = t2 >> 7, k = t2 & 127; v = f2bf(nw1[k * HD + n]); }
      else if (j < NW3T) { int t2 = j - NW2T, n = t2 >> 7, k = t2 & 127; v = f2bf(nw2[k * HD + n]); }
      else               { int t2 = j - NW3T, n = t2 >> 7, k = t2 & 127; v = f2bf(nw3[k * HD + n]); }
      wbuf[j] = v;
    }
  }
}

// ---------------- shared MLP helpers ----------------
__device__ inline void zacc(f32x4 acc[4][2]) {
  #pragma unroll
  for (int i = 0; i < 4; ++i) {
    #pragma unroll
    for (int j = 0; j < 2; ++j) { f32x4 z = {0.f, 0.f, 0.f, 0.f}; acc[i][j] = z; }
  }
}

// 128-wide K chunk (4 ksteps of 32). A: LDS [64][136] bf16. Wt: [128][Kw] bf16 (global).
__device__ inline void mlp_ksteps(const short* __restrict__ Ab, const short* __restrict__ Wt,
                                  int Kw, int kglob0, f32x4 acc[4][2], int lr, int kg, int w)
{
  const short* ap = Ab + lr * 136 + kg * 8;
  const short* wp = Wt + (w * 32 + lr) * Kw + kglob0 + kg * 8;
  #pragma unroll
  for (int ks = 0; ks < 4; ++ks) {
    short8 a[4], b[2];
    #pragma unroll
    for (int mf = 0; mf < 4; ++mf) a[mf] = *(const short8*)(ap + mf * (16 * 136) + ks * 32);
    #pragma unroll
    for (int nf = 0; nf < 2; ++nf) b[nf] = *(const short8*)(wp + nf * 16 * Kw + ks * 32);
    #pragma unroll
    for (int mf = 0; mf < 4; ++mf) {
      #pragma unroll
      for (int nf = 0; nf < 2; ++nf)
        acc[mf][nf] = __builtin_amdgcn_mfma_f32_16x16x32_bf16(a[mf], b[nf], acc[mf][nf], 0, 0, 0);
    }
  }
}

__device__ inline void wb_bf16(short* __restrict__ dst, const float* __restrict__ bias,
                               f32x4 acc[4][2], int lr, int kg, int w, bool relu)
{
  #pragma unroll
  for (int nf = 0; nf < 2; ++nf) {
    const int col = w * 32 + nf * 16 + lr;
    const float bv = bias[col];
    #pragma unroll
    for (int mf = 0; mf < 4; ++mf) {
      #pragma unroll
      for (int r = 0; r < 4; ++r) {
        const int row = mf * 16 + kg * 4 + r;
        float v = acc[mf][nf][r] + bv;
        if (relu) v = fmaxf(v, 0.f);
        dst[row * 136 + col] = f2bf(v);
      }
    }
  }
}

__device__ inline void wb_f32(float* __restrict__ dst, const float* __restrict__ bias,
                              f32x4 acc[4][2], int lr, int kg, int w)
{
  #pragma unroll
  for (int nf = 0; nf < 2; ++nf) {
    const int col = w * 32 + nf * 16 + lr;
    const float bv = bias[col];
    #pragma unroll
    for (int mf = 0; mf < 4; ++mf) {
      #pragma unroll
      for (int r = 0; r < 4; ++r) {
        const int row = mf * 16 + kg * 4 + r;
        dst[row * 132 + col] = acc[mf][nf][r] + bv;
      }
    }
  }
}

// ---------------- edge kernel: gather -> MLP(384->128->128->128->128) -> LN -> residual + scatter ----------------
__global__ __launch_bounds__(256, 4) void edge_kernel(
    const float* __restrict__ nodef, const float* __restrict__ eattr,
    const int* __restrict__ eidx,
    const float* __restrict__ b0, const float* __restrict__ b1,
    const float* __restrict__ b2, const float* __restrict__ b3,
    const float* __restrict__ gam, const float* __restrict__ bet,
    const short* __restrict__ wbuf, float* __restrict__ out)
{
  __shared__ short lds[2 * 64 * 136];
  short* B1 = lds;
  short* B2 = lds + 64 * 136;
  float* Hb = (float*)lds;   // 64 x 132 f32, overlays B1+B2 (used only after final barrier)

  const int t = (int)threadIdx.x;
  const int lane = t & 63;
  const int w = t >> 6;
  const int lr = lane & 15;
  const int kg = lane >> 4;
  const int e0 = (int)blockIdx.x * 64;
  const int* senders = eidx;
  const int* recvs = eidx + N_EDGES_C;

  f32x4 acc[4][2];
  zacc(acc);

  // ---- layer 0: K=384 in 3 chunks (senders / receivers / edge_attr) ----
  #pragma unroll 1
  for (int c = 0; c < 3; ++c) {
    #pragma unroll
    for (int p = 0; p < 4; ++p) {
      int idx = p * 256 + t;
      int row = idx >> 4;
      int kc = idx & 15;
      int e = e0 + row;
      const float* src;
      if (c == 0)      src = nodef + (size_t)senders[e] * HD + kc * 8;
      else if (c == 1) src = nodef + (size_t)recvs[e] * HD + kc * 8;
      else             src = eattr + (size_t)e * HD + kc * 8;
      f32x4 v0 = *(const f32x4*)src;
      f32x4 v1 = *(const f32x4*)(src + 4);
      short8 sv;
      sv[0] = f2bf(v0[0]); sv[1] = f2bf(v0[1]); sv[2] = f2bf(v0[2]); sv[3] = f2bf(v0[3]);
      sv[4] = f2bf(v1[0]); sv[5] = f2bf(v1[1]); sv[6] = f2bf(v1[2]); sv[7] = f2bf(v1[3]);
      *(short8*)(B1 + row * 136 + kc * 8) = sv;
    }
    __syncthreads();
    mlp_ksteps(B1, wbuf + EW0T, 384, c * 128, acc, lr, kg, w);
    __syncthreads();
  }
  wb_bf16(B2, b0, acc, lr, kg, w, true);
  __syncthreads();

  zacc(acc);
  mlp_ksteps(B2, wbuf + EW1T, 128, 0, acc, lr, kg, w);
  wb_bf16(B1, b1, acc, lr, kg, w, true);
  __syncthreads();

  zacc(acc);
  mlp_ksteps(B1, wbuf + EW2T, 128, 0, acc, lr, kg, w);
  wb_bf16(B2, b2, acc, lr, kg, w, true);
  __syncthreads();

  zacc(acc);
  mlp_ksteps(B2, wbuf + EW3T, 128, 0, acc, lr, kg, w);
  __syncthreads();
  wb_f32(Hb, b3, acc, lr, kg, w);
  __syncthreads();

  // ---- LayerNorm + residual + scatter-add ----
  {
    const int row = t >> 2;
    const int q = t & 3;
    const int e = e0 + row;
    const float* hr = Hb + row * 132 + q * 32;
    float sum = 0.f, ss = 0.f;
    #pragma unroll
    for (int jj = 0; jj < 8; ++jj) {
      f32x4 v = *(const f32x4*)(hr + jj * 4);
      sum += v[0] + v[1] + v[2] + v[3];
      ss  += v[0] * v[0] + v[1] * v[1] + v[2] * v[2] + v[3] * v[3];
    }
    sum += __shfl_xor(sum, 1, 64); sum += __shfl_xor(sum, 2, 64);
    ss  += __shfl_xor(ss, 1, 64);  ss  += __shfl_xor(ss, 2, 64);
    const float mu = sum * (1.f / 128.f);
    const float var = ss * (1.f / 128.f) - mu * mu;
    const float rs = rsqrtf(var + 1e-5f);
    const int rv = recvs[e];
    float* aggp = out + OUT_NODE + (size_t)rv * HD + q * 32;
    float* oute = out + OUT_EDGE + (size_t)e * HD + q * 32;
    const float* eap = eattr + (size_t)e * HD + q * 32;
    const float* gp = gam + q * 32;
    const float* bp = bet + q * 32;
    #pragma unroll
    for (int jj = 0; jj < 8; ++jj) {
      f32x4 v  = *(const f32x4*)(hr + jj * 4);
      f32x4 g4 = *(const f32x4*)(gp + jj * 4);
      f32x4 b4 = *(const f32x4*)(bp + jj * 4);
      f32x4 ea = *(const f32x4*)(eap + jj * 4);
      f32x4 o, res;
      #pragma unroll
      for (int x = 0; x < 4; ++x) { o[x] = (v[x] - mu) * rs * g4[x] + b4[x]; res[x] = ea[x] + o[x]; }
      *(f32x4*)(oute + jj * 4) = res;
      atomicAdd(aggp + jj * 4 + 0, o[0]);
      atomicAdd(aggp + jj * 4 + 1, o[1]);
      atomicAdd(aggp + jj * 4 + 2, o[2]);
      atomicAdd(aggp + jj * 4 + 3, o[3]);
    }
  }
}

// ---------------- node kernel: [node_features | agg] -> MLP(256->...) -> LN -> residual ----------------
__global__ __launch_bounds__(256, 4) void node_kernel(
    const float* __restrict__ nodef,
    const float* __restrict__ b0, const float* __restrict__ b1,
    const float* __restrict__ b2, const float* __restrict__ b3,
    const float* __restrict__ gam, const float* __restrict__ bet,
    const short* __restrict__ wbuf, float* __restrict__ out)
{
  __shared__ short lds[2 * 64 * 136];
  short* B1 = lds;
  short* B2 = lds + 64 * 136;
  float* Hb = (float*)lds;

  const int t = (int)threadIdx.x;
  const int lane = t & 63;
  const int w = t >> 6;
  const int lr = lane & 15;
  const int kg = lane >> 4;
  const int n0 = (int)blockIdx.x * 64;

  f32x4 acc[4][2];
  zacc(acc);

  // ---- layer 0: K=256 in 2 chunks (node_features / agg) ----
  #pragma unroll 1
  for (int c = 0; c < 2; ++c) {
    #pragma unroll
    for (int p = 0; p < 4; ++p) {
      int idx = p * 256 + t;
      int row = idx >> 4;
      int kc = idx & 15;
      int n = n0 + row;
      int ns = n < N_NODES_C ? n : 0;
      const float* src = (c == 0) ? (nodef + (size_t)ns * HD + kc * 8)
                                  : (out + OUT_NODE + (size_t)ns * HD + kc * 8);
      f32x4 v0 = *(const f32x4*)src;
      f32x4 v1 = *(const f32x4*)(src + 4);
      short8 sv;
      sv[0] = f2bf(v0[0]); sv[1] = f2bf(v0[1]); sv[2] = f2bf(v0[2]); sv[3] = f2bf(v0[3]);
      sv[4] = f2bf(v1[0]); sv[5] = f2bf(v1[1]); sv[6] = f2bf(v1[2]); sv[7] = f2bf(v1[3]);
      *(short8*)(B1 + row * 136 + kc * 8) = sv;
    }
    __syncthreads();
    mlp_ksteps(B1, wbuf + NW0T, 256, c * 128, acc, lr, kg, w);
    __syncthreads();
  }
  wb_bf16(B2, b0, acc, lr, kg, w, true);
  __syncthreads();

  zacc(acc);
  mlp_ksteps(B2, wbuf + NW1T, 128, 0, acc, lr, kg, w);
  wb_bf16(B1, b1, acc, lr, kg, w, true);
  __syncthreads();

  zacc(acc);
  mlp_ksteps(B1, wbuf + NW2T, 128, 0, acc, lr, kg, w);
  wb_bf16(B2, b2, acc, lr, kg, w, true);
  __syncthreads();

  zacc(acc);
  mlp_ksteps(B2, wbuf + NW3T, 128, 0, acc, lr, kg, w);
  __syncthreads();
  wb_f32(Hb, b3, acc, lr, kg, w);
  __syncthreads();

  // ---- LayerNorm + residual (overwrites agg region with final node output) ----
  {
    const int row = t >> 2;
    const int q = t & 3;
    const int n = n0 + row;
    const float* hr = Hb + row * 132 + q * 32;
    float sum = 0.f, ss = 0.f;
    #pragma unroll
    for (int jj = 0; jj < 8; ++jj) {
      f32x4 v = *(const f32x4*)(hr + jj * 4);
      sum += v[0] + v[1] + v[2] + v[3];
      ss  += v[0] * v[0] + v[1] * v[1] + v[2] * v[2] + v[3] * v[3];
    }
    sum += __shfl_xor(sum, 1, 64); sum += __shfl_xor(sum, 2, 64);
    ss  += __shfl_xor(ss, 1, 64);  ss  += __shfl_xor(ss, 2, 64);
    const float mu = sum * (1.f / 128.f);
    const float var = ss * (1.f / 128.f) - mu * mu;
    const float rs = rsqrtf(var + 1e-5f);
    if (n < N_NODES_C) {
      const float* nfp = nodef + (size_t)n * HD + q * 32;
      float* outp = out + OUT_NODE + (size_t)n * HD + q * 32;
      const float* gp = gam + q * 32;
      const float* bp = bet + q * 32;
      #pragma unroll
      for (int jj = 0; jj < 8; ++jj) {
        f32x4 v  = *(const f32x4*)(hr + jj * 4);
        f32x4 g4 = *(const f32x4*)(gp + jj * 4);
        f32x4 b4 = *(const f32x4*)(bp + jj * 4);
        f32x4 nf4 = *(const f32x4*)(nfp + jj * 4);
        f32x4 res;
        #pragma unroll
        for (int x = 0; x < 4; ++x) res[x] = nf4[x] + (v[x] - mu) * rs * g4[x] + b4[x];
        *(f32x4*)(outp + jj * 4) = res;
      }
    }
  }
}

extern "C" void kernel_launch(void* const* d_in, const int* in_sizes, int n_in,
                              void* d_out, int out_size, void* d_ws, size_t ws_size,
                              hipStream_t stream) {
  const float* nodef = (const float*)d_in[0];
  const float* eattr = (const float*)d_in[1];
  const int*   eidx  = (const int*)d_in[2];
  const float* e_w0 = (const float*)d_in[3];
  const float* e_b0 = (const float*)d_in[4];
  const float* e_w1 = (const float*)d_in[5];
  const float* e_b1 = (const float*)d_in[6];
  const float* e_w2 = (const float*)d_in[7];
  const float* e_b2 = (const float*)d_in[8];
  const float* e_w3 = (const float*)d_in[9];
  const float* e_b3 = (const float*)d_in[10];
  const float* e_g  = (const float*)d_in[11];
  const float* e_be = (const float*)d_in[12];
  const float* n_w0 = (const float*)d_in[13];
  const float* n_b0 = (const float*)d_in[14];
  const float* n_w1 = (const float*)d_in[15];
  const float* n_b1 = (const float*)d_in[16];
  const float* n_w2 = (const float*)d_in[17];
  const float* n_b2 = (const float*)d_in[18];
  const float* n_w3 = (const float*)d_in[19];
  const float* n_b3 = (const float*)d_in[20];
  const float* n_g  = (const float*)d_in[21];
  const float* n_be = (const float*)d_in[22];

  float* out = (float*)d_out;
  short* wbuf = (short*)d_ws;

  prep_kernel<<<4096, 256, 0, stream>>>(e_w0, e_w1, e_w2, e_w3, n_w0, n_w1, n_w2, n_w3,
                                        eidx, out, wbuf);
  edge_kernel<<<N_EDGES_C / 64, 256, 0, stream>>>(nodef, eattr, eidx,
                                                  e_b0, e_b1, e_b2, e_b3, e_g, e_be,
                                                  wbuf, out);
  node_kernel<<<(N_NODES_C + 63) / 64, 256, 0, stream>>>(nodef,
                                                         n_b0, n_b1, n_b2, n_b3, n_g, n_be,
                                                         wbuf, out);
}

// Round 2
// 849.138 us; speedup vs baseline: 5.1594x; 5.1594x over previous
//
#include <hip/hip_runtime.h>

#define N_NODES_C 50000
#define N_EDGES_C 640000
#define HD 128

typedef float f32x4 __attribute__((ext_vector_type(4)));
typedef float f32x2 __attribute__((ext_vector_type(2)));
typedef short short8 __attribute__((ext_vector_type(8)));

// d_out layout (floats): [node_out 6.4M][edge_index 1.28M][edge_out 81.92M]
#define OUT_NODE 0
#define OUT_IDX  6400000
#define OUT_EDGE 7680000

// workspace layout part 1 (shorts = bf16), transposed weights [n][k]
#define EW0T 0        // 128x384
#define EW1T 49152    // 128x128
#define EW2T 65536
#define EW3T 81920
#define NW0T 98304    // 128x256
#define NW1T 131072
#define NW2T 147456
#define NW3T 163840
#define WTOT 180224   // shorts = 360448 bytes

// workspace layout part 2 (ints; int-index into d_ws)
#define OFFS_I  98304    // 50001 ints: CSR row starts
#define CURS_I  148352   // 50000 ints: counts -> cursor -> row ends
#define ELIST_I 198400   // 640000 ints: edge ids sorted by receiver
// total = 838400 ints = 3.35 MB

__device__ inline short f2bf(float f) {
  unsigned u = __builtin_bit_cast(unsigned, f);
  u += 0x7fffu + ((u >> 16) & 1u);   // RNE
  return (short)(u >> 16);
}

// ---------------- prep: cast edge_index->float, zero CSR counts, transpose+cast weights ----------------
__global__ void prep_kernel(const float* __restrict__ ew0, const float* __restrict__ ew1,
                            const float* __restrict__ ew2, const float* __restrict__ ew3,
                            const float* __restrict__ nw0, const float* __restrict__ nw1,
                            const float* __restrict__ nw2, const float* __restrict__ nw3,
                            const int* __restrict__ eidx,
                            float* __restrict__ out, short* __restrict__ wbuf)
{
  int* wsi = (int*)wbuf;
  const int total = 1280000 + 50000 + WTOT;
  for (int i = blockIdx.x * blockDim.x + threadIdx.x; i < total; i += gridDim.x * blockDim.x) {
    if (i < 1280000) {
      out[OUT_IDX + i] = (float)eidx[i];           // edge_index pass-through
    } else if (i < 1330000) {
      wsi[CURS_I + (i - 1280000)] = 0;             // CSR counts
    } else {
      int j = i - 1330000;
      short v;
      if (j < EW1T)      { int n = j / 384,  k = j - n * 384; v = f2bf(ew0[k * HD + n]); }
      else if (j < EW2T) { int t2 = j - EW1T, n = t2 >> 7, k = t2 & 127; v = f2bf(ew1[k * HD + n]); }
      else if (j < EW3T) { int t2 = j - EW2T, n = t2 >> 7, k = t2 & 127; v = f2bf(ew2[k * HD + n]); }
      else if (j < NW0T) { int t2 = j - EW3T, n = t2 >> 7, k = t2 & 127; v = f2bf(ew3[k * HD + n]); }
      else if (j < NW1T) { int t2 = j - NW0T, n = t2 >> 8, k = t2 & 255; v = f2bf(nw0[k * HD + n]); }
      else if (j < NW2T) { int t2 = j - NW1T, n = t2 >> 7, k = t2 & 127; v = f2bf(nw1[k * HD + n]); }
      else if (j < NW3T) { int t2 = j - NW2T, n = t2 >> 7, k = t2 & 127; v = f2bf(nw2[k * HD + n]); }
      else               { int t2 = j - NW3T, n = t2 >> 7, k = t2 & 127; v = f2bf(nw3[k * HD + n]); }
      wbuf[j] = v;
    }
  }
}

// ---------------- CSR build: histogram / scan / fill ----------------
__global__ void hist_kernel(const int* __restrict__ eidx, short* __restrict__ wbuf) {
  int* counts = (int*)wbuf + CURS_I;
  int e = blockIdx.x * blockDim.x + threadIdx.x;
  if (e < N_EDGES_C) atomicAdd(&counts[eidx[N_EDGES_C + e]], 1);
}

__global__ void scan_kernel(short* __restrict__ wbuf) {
  int* wsi = (int*)wbuf;
  int* counts = wsi + CURS_I;   // becomes cursor
  int* offs = wsi + OFFS_I;
  __shared__ int tsum[1024];
  const int t = (int)threadIdx.x;
  const int per = (N_NODES_C + 1023) / 1024;  // 49
  const int base = t * per;
  const int lim = base + per < N_NODES_C ? base + per : N_NODES_C;
  int s = 0;
  for (int j = base; j < lim; ++j) s += counts[j];
  tsum[t] = s;
  __syncthreads();
  for (int off = 1; off < 1024; off <<= 1) {
    int v = tsum[t];
    int add = (t >= off) ? tsum[t - off] : 0;
    __syncthreads();
    tsum[t] = v + add;
    __syncthreads();
  }
  int run = (t == 0) ? 0 : tsum[t - 1];
  for (int j = base; j < lim; ++j) {
    int c = counts[j];
    offs[j] = run;
    counts[j] = run;   // cursor init
    run += c;
  }
  if (t == 1023) offs[N_NODES_C] = run;
}

__global__ void fill_kernel(const int* __restrict__ eidx, short* __restrict__ wbuf) {
  int* wsi = (int*)wbuf;
  int* cursor = wsi + CURS_I;
  int* elist = wsi + ELIST_I;
  int e = blockIdx.x * blockDim.x + threadIdx.x;
  if (e < N_EDGES_C) {
    int r = eidx[N_EDGES_C + e];
    int pos = atomicAdd(&cursor[r], 1);
    elist[pos] = e;
  }
}

// ---------------- shared MLP helpers ----------------
__device__ inline void zacc(f32x4 acc[4][2]) {
  #pragma unroll
  for (int i = 0; i < 4; ++i) {
    #pragma unroll
    for (int j = 0; j < 2; ++j) { f32x4 z = {0.f, 0.f, 0.f, 0.f}; acc[i][j] = z; }
  }
}

// 128-wide K chunk (4 ksteps of 32). A: LDS [64][136] bf16. Wt: [128][Kw] bf16 (global).
__device__ inline void mlp_ksteps(const short* __restrict__ Ab, const short* __restrict__ Wt,
                                  int Kw, int kglob0, f32x4 acc[4][2], int lr, int kg, int w)
{
  const short* ap = Ab + lr * 136 + kg * 8;
  const short* wp = Wt + (w * 32 + lr) * Kw + kglob0 + kg * 8;
  #pragma unroll
  for (int ks = 0; ks < 4; ++ks) {
    short8 a[4], b[2];
    #pragma unroll
    for (int mf = 0; mf < 4; ++mf) a[mf] = *(const short8*)(ap + mf * (16 * 136) + ks * 32);
    #pragma unroll
    for (int nf = 0; nf < 2; ++nf) b[nf] = *(const short8*)(wp + nf * 16 * Kw + ks * 32);
    #pragma unroll
    for (int mf = 0; mf < 4; ++mf) {
      #pragma unroll
      for (int nf = 0; nf < 2; ++nf)
        acc[mf][nf] = __builtin_amdgcn_mfma_f32_16x16x32_bf16(a[mf], b[nf], acc[mf][nf], 0, 0, 0);
    }
  }
}

__device__ inline void wb_bf16(short* __restrict__ dst, const float* __restrict__ bias,
                               f32x4 acc[4][2], int lr, int kg, int w, bool relu)
{
  #pragma unroll
  for (int nf = 0; nf < 2; ++nf) {
    const int col = w * 32 + nf * 16 + lr;
    const float bv = bias[col];
    #pragma unroll
    for (int mf = 0; mf < 4; ++mf) {
      #pragma unroll
      for (int r = 0; r < 4; ++r) {
        const int row = mf * 16 + kg * 4 + r;
        float v = acc[mf][nf][r] + bv;
        if (relu) v = fmaxf(v, 0.f);
        dst[row * 136 + col] = f2bf(v);
      }
    }
  }
}

__device__ inline void wb_f32(float* __restrict__ dst, const float* __restrict__ bias,
                              f32x4 acc[4][2], int lr, int kg, int w)
{
  #pragma unroll
  for (int nf = 0; nf < 2; ++nf) {
    const int col = w * 32 + nf * 16 + lr;
    const float bv = bias[col];
    #pragma unroll
    for (int mf = 0; mf < 4; ++mf) {
      #pragma unroll
      for (int r = 0; r < 4; ++r) {
        const int row = mf * 16 + kg * 4 + r;
        dst[row * 132 + col] = acc[mf][nf][r] + bv;
      }
    }
  }
}

// ---------------- edge kernel: gather -> MLP(384->128->128->128->128) -> LN -> residual ----------------
__global__ __launch_bounds__(256, 4) void edge_kernel(
    const float* __restrict__ nodef, const float* __restrict__ eattr,
    const int* __restrict__ eidx,
    const float* __restrict__ b0, const float* __restrict__ b1,
    const float* __restrict__ b2, const float* __restrict__ b3,
    const float* __restrict__ gam, const float* __restrict__ bet,
    const short* __restrict__ wbuf, float* __restrict__ out)
{
  __shared__ short lds[2 * 64 * 136];
  short* B1 = lds;
  short* B2 = lds + 64 * 136;
  float* Hb = (float*)lds;   // 64 x 132 f32, overlays B1+B2 (used only after final barrier)

  const int t = (int)threadIdx.x;
  const int lane = t & 63;
  const int w = t >> 6;
  const int lr = lane & 15;
  const int kg = lane >> 4;
  const int e0 = (int)blockIdx.x * 64;
  const int* senders = eidx;
  const int* recvs = eidx + N_EDGES_C;

  f32x4 acc[4][2];
  zacc(acc);

  // ---- layer 0: K=384 in 3 chunks (senders / receivers / edge_attr) ----
  #pragma unroll 1
  for (int c = 0; c < 3; ++c) {
    #pragma unroll
    for (int p = 0; p < 4; ++p) {
      int idx = p * 256 + t;
      int row = idx >> 4;
      int kc = idx & 15;
      int e = e0 + row;
      const float* src;
      if (c == 0)      src = nodef + (size_t)senders[e] * HD + kc * 8;
      else if (c == 1) src = nodef + (size_t)recvs[e] * HD + kc * 8;
      else             src = eattr + (size_t)e * HD + kc * 8;
      f32x4 v0 = *(const f32x4*)src;
      f32x4 v1 = *(const f32x4*)(src + 4);
      short8 sv;
      sv[0] = f2bf(v0[0]); sv[1] = f2bf(v0[1]); sv[2] = f2bf(v0[2]); sv[3] = f2bf(v0[3]);
      sv[4] = f2bf(v1[0]); sv[5] = f2bf(v1[1]); sv[6] = f2bf(v1[2]); sv[7] = f2bf(v1[3]);
      *(short8*)(B1 + row * 136 + kc * 8) = sv;
    }
    __syncthreads();
    mlp_ksteps(B1, wbuf + EW0T, 384, c * 128, acc, lr, kg, w);
    __syncthreads();
  }
  wb_bf16(B2, b0, acc, lr, kg, w, true);
  __syncthreads();

  zacc(acc);
  mlp_ksteps(B2, wbuf + EW1T, 128, 0, acc, lr, kg, w);
  wb_bf16(B1, b1, acc, lr, kg, w, true);
  __syncthreads();

  zacc(acc);
  mlp_ksteps(B1, wbuf + EW2T, 128, 0, acc, lr, kg, w);
  wb_bf16(B2, b2, acc, lr, kg, w, true);
  __syncthreads();

  zacc(acc);
  mlp_ksteps(B2, wbuf + EW3T, 128, 0, acc, lr, kg, w);
  __syncthreads();
  wb_f32(Hb, b3, acc, lr, kg, w);
  __syncthreads();

  // ---- LayerNorm + residual store (NO scatter — agg is gathered later via CSR) ----
  {
    const int row = t >> 2;
    const int q = t & 3;
    const int e = e0 + row;
    const float* hr = Hb + row * 132 + q * 32;
    float sum = 0.f, ss = 0.f;
    #pragma unroll
    for (int jj = 0; jj < 8; ++jj) {
      f32x4 v = *(const f32x4*)(hr + jj * 4);
      sum += v[0] + v[1] + v[2] + v[3];
      ss  += v[0] * v[0] + v[1] * v[1] + v[2] * v[2] + v[3] * v[3];
    }
    sum += __shfl_xor(sum, 1, 64); sum += __shfl_xor(sum, 2, 64);
    ss  += __shfl_xor(ss, 1, 64);  ss  += __shfl_xor(ss, 2, 64);
    const float mu = sum * (1.f / 128.f);
    const float var = ss * (1.f / 128.f) - mu * mu;
    const float rs = rsqrtf(var + 1e-5f);
    float* oute = out + OUT_EDGE + (size_t)e * HD + q * 32;
    const float* eap = eattr + (size_t)e * HD + q * 32;
    const float* gp = gam + q * 32;
    const float* bp = bet + q * 32;
    #pragma unroll
    for (int jj = 0; jj < 8; ++jj) {
      f32x4 v  = *(const f32x4*)(hr + jj * 4);
      f32x4 g4 = *(const f32x4*)(gp + jj * 4);
      f32x4 b4 = *(const f32x4*)(bp + jj * 4);
      f32x4 ea = *(const f32x4*)(eap + jj * 4);
      f32x4 res;
      #pragma unroll
      for (int x = 0; x < 4; ++x) res[x] = ea[x] + ((v[x] - mu) * rs * g4[x] + b4[x]);
      *(f32x4*)(oute + jj * 4) = res;
    }
  }
}

// ---------------- agg kernel: CSR gather-sum, one wave per node ----------------
// agg[n] = sum over edges e with recv==n of (edge_out[e] - eattr[e])
__global__ __launch_bounds__(256, 8) void agg_kernel(
    const float* __restrict__ eattr, const short* __restrict__ wbuf,
    float* __restrict__ out)
{
  const int* wsi = (const int*)wbuf;
  const int* offs = wsi + OFFS_I;
  const int* ends = wsi + CURS_I;   // cursor after fill == row end
  const int* elist = wsi + ELIST_I;

  const int t = (int)threadIdx.x;
  const int lane = t & 63;
  const int n = (int)blockIdx.x * 4 + (t >> 6);
  if (n >= N_NODES_C) return;

  const int start = offs[n];
  const int end = ends[n];
  f32x2 acc = {0.f, 0.f};
  const float* eo_base = out + OUT_EDGE + lane * 2;
  const float* ea_base = eattr + lane * 2;
  for (int j = start; j < end; ++j) {
    const int e = elist[j];
    f32x2 eo = *(const f32x2*)(eo_base + (size_t)e * HD);
    f32x2 ea = *(const f32x2*)(ea_base + (size_t)e * HD);
    acc[0] += eo[0] - ea[0];
    acc[1] += eo[1] - ea[1];
  }
  *(f32x2*)(out + OUT_NODE + (size_t)n * HD + lane * 2) = acc;
}

// ---------------- node kernel: [node_features | agg] -> MLP(256->...) -> LN -> residual ----------------
__global__ __launch_bounds__(256, 4) void node_kernel(
    const float* __restrict__ nodef,
    const float* __restrict__ b0, const float* __restrict__ b1,
    const float* __restrict__ b2, const float* __restrict__ b3,
    const float* __restrict__ gam, const float* __restrict__ bet,
    const short* __restrict__ wbuf, float* __restrict__ out)
{
  __shared__ short lds[2 * 64 * 136];
  short* B1 = lds;
  short* B2 = lds + 64 * 136;
  float* Hb = (float*)lds;

  const int t = (int)threadIdx.x;
  const int lane = t & 63;
  const int w = t >> 6;
  const int lr = lane & 15;
  const int kg = lane >> 4;
  const int n0 = (int)blockIdx.x * 64;

  f32x4 acc[4][2];
  zacc(acc);

  // ---- layer 0: K=256 in 2 chunks (node_features / agg) ----
  #pragma unroll 1
  for (int c = 0; c < 2; ++c) {
    #pragma unroll
    for (int p = 0; p < 4; ++p) {
      int idx = p * 256 + t;
      int row = idx >> 4;
      int kc = idx & 15;
      int n = n0 + row;
      int ns = n < N_NODES_C ? n : 0;
      const float* src = (c == 0) ? (nodef + (size_t)ns * HD + kc * 8)
                                  : (out + OUT_NODE + (size_t)ns * HD + kc * 8);
      f32x4 v0 = *(const f32x4*)src;
      f32x4 v1 = *(const f32x4*)(src + 4);
      short8 sv;
      sv[0] = f2bf(v0[0]); sv[1] = f2bf(v0[1]); sv[2] = f2bf(v0[2]); sv[3] = f2bf(v0[3]);
      sv[4] = f2bf(v1[0]); sv[5] = f2bf(v1[1]); sv[6] = f2bf(v1[2]); sv[7] = f2bf(v1[3]);
      *(short8*)(B1 + row * 136 + kc * 8) = sv;
    }
    __syncthreads();
    mlp_ksteps(B1, wbuf + NW0T, 256, c * 128, acc, lr, kg, w);
    __syncthreads();
  }
  wb_bf16(B2, b0, acc, lr, kg, w, true);
  __syncthreads();

  zacc(acc);
  mlp_ksteps(B2, wbuf + NW1T, 128, 0, acc, lr, kg, w);
  wb_bf16(B1, b1, acc, lr, kg, w, true);
  __syncthreads();

  zacc(acc);
  mlp_ksteps(B1, wbuf + NW2T, 128, 0, acc, lr, kg, w);
  wb_bf16(B2, b2, acc, lr, kg, w, true);
  __syncthreads();

  zacc(acc);
  mlp_ksteps(B2, wbuf + NW3T, 128, 0, acc, lr, kg, w);
  __syncthreads();
  wb_f32(Hb, b3, acc, lr, kg, w);
  __syncthreads();

  // ---- LayerNorm + residual (overwrites agg region with final node output) ----
  {
    const int row = t >> 2;
    const int q = t & 3;
    const int n = n0 + row;
    const float* hr = Hb + row * 132 + q * 32;
    float sum = 0.f, ss = 0.f;
    #pragma unroll
    for (int jj = 0; jj < 8; ++jj) {
      f32x4 v = *(const f32x4*)(hr + jj * 4);
      sum += v[0] + v[1] + v[2] + v[3];
      ss  += v[0] * v[0] + v[1] * v[1] + v[2] * v[2] + v[3] * v[3];
    }
    sum += __shfl_xor(sum, 1, 64); sum += __shfl_xor(sum, 2, 64);
    ss  += __shfl_xor(ss, 1, 64);  ss  += __shfl_xor(ss, 2, 64);
    const float mu = sum * (1.f / 128.f);
    const float var = ss * (1.f / 128.f) - mu * mu;
    const float rs = rsqrtf(var + 1e-5f);
    if (n < N_NODES_C) {
      const float* nfp = nodef + (size_t)n * HD + q * 32;
      float* outp = out + OUT_NODE + (size_t)n * HD + q * 32;
      const float* gp = gam + q * 32;
      const float* bp = bet + q * 32;
      #pragma unroll
      for (int jj = 0; jj < 8; ++jj) {
        f32x4 v  = *(const f32x4*)(hr + jj * 4);
        f32x4 g4 = *(const f32x4*)(gp + jj * 4);
        f32x4 b4 = *(const f32x4*)(bp + jj * 4);
        f32x4 nf4 = *(const f32x4*)(nfp + jj * 4);
        f32x4 res;
        #pragma unroll
        for (int x = 0; x < 4; ++x) res[x] = nf4[x] + (v[x] - mu) * rs * g4[x] + b4[x];
        *(f32x4*)(outp + jj * 4) = res;
      }
    }
  }
}

extern "C" void kernel_launch(void* const* d_in, const int* in_sizes, int n_in,
                              void* d_out, int out_size, void* d_ws, size_t ws_size,
                              hipStream_t stream) {
  const float* nodef = (const float*)d_in[0];
  const float* eattr = (const float*)d_in[1];
  const int*   eidx  = (const int*)d_in[2];
  const float* e_w0 = (const float*)d_in[3];
  const float* e_b0 = (const float*)d_in[4];
  const float* e_w1 = (const float*)d_in[5];
  const float* e_b1 = (const float*)d_in[6];
  const float* e_w2 = (const float*)d_in[7];
  const float* e_b2 = (const float*)d_in[8];
  const float* e_w3 = (const float*)d_in[9];
  const float* e_b3 = (const float*)d_in[10];
  const float* e_g  = (const float*)d_in[11];
  const float* e_be = (const float*)d_in[12];
  const float* n_w0 = (const float*)d_in[13];
  const float* n_b0 = (const float*)d_in[14];
  const float* n_w1 = (const float*)d_in[15];
  const float* n_b1 = (const float*)d_in[16];
  const float* n_w2 = (const float*)d_in[17];
  const float* n_b2 = (const float*)d_in[18];
  const float* n_w3 = (const float*)d_in[19];
  const float* n_b3 = (const float*)d_in[20];
  const float* n_g  = (const float*)d_in[21];
  const float* n_be = (const float*)d_in[22];

  float* out = (float*)d_out;
  short* wbuf = (short*)d_ws;

  prep_kernel<<<2048, 256, 0, stream>>>(e_w0, e_w1, e_w2, e_w3, n_w0, n_w1, n_w2, n_w3,
                                        eidx, out, wbuf);
  hist_kernel<<<(N_EDGES_C + 255) / 256, 256, 0, stream>>>(eidx, wbuf);
  scan_kernel<<<1, 1024, 0, stream>>>(wbuf);
  fill_kernel<<<(N_EDGES_C + 255) / 256, 256, 0, stream>>>(eidx, wbuf);
  edge_kernel<<<N_EDGES_C / 64, 256, 0, stream>>>(nodef, eattr, eidx,
                                                  e_b0, e_b1, e_b2, e_b3, e_g, e_be,
                                                  wbuf, out);
  agg_kernel<<<(N_NODES_C + 3) / 4, 256, 0, stream>>>(eattr, wbuf, out);
  node_kernel<<<(N_NODES_C + 63) / 64, 256, 0, stream>>>(nodef,
                                                         n_b0, n_b1, n_b2, n_b3, n_g, n_be,
                                                         wbuf, out);
}

// Round 3
// 763.863 us; speedup vs baseline: 5.7353x; 1.1116x over previous
//
#include <hip/hip_runtime.h>

#define N_NODES_C 50000
#define N_EDGES_C 640000
#define HD 128

typedef float f32x4 __attribute__((ext_vector_type(4)));
typedef float f32x2 __attribute__((ext_vector_type(2)));
typedef short short8 __attribute__((ext_vector_type(8)));

// d_out layout (floats): [node_out 6.4M][edge_index 1.28M][edge_out 81.92M]
#define OUT_NODE 0
#define OUT_IDX  6400000
#define OUT_EDGE 7680000

// workspace layout part 1 (shorts = bf16), transposed weights [n][k]
#define EW0T 0        // [0,16384): We^T [128][128]; [16384,49152): WP^T [256][128] (Ps|Pr)
#define WPT  16384
#define EW1T 49152    // 128x128
#define EW2T 65536
#define EW3T 81920
#define NW0T 98304    // 128x256
#define NW1T 131072
#define NW2T 147456
#define NW3T 163840
#define WTOT 180224   // shorts

// workspace layout part 2 (ints; int-index into d_ws)
#define OFFS_I  98304    // 50001 ints: CSR row starts
#define CURS_I  148352   // 50000 ints: counts -> cursor -> row ends
#define ELIST_I 198400   // 640000 ints
// ints end at 838400 (byte 3353600)

// workspace part 3: P table, bf16 [50000][256] (Ps cols 0-127, Pr cols 128-255)
#define PTAB_S 1676800   // short index (byte 3353600); ends ~29 MB

__device__ inline short f2bf(float f) {
  unsigned u = __builtin_bit_cast(unsigned, f);
  u += 0x7fffu + ((u >> 16) & 1u);   // RNE
  return (short)(u >> 16);
}
__device__ inline float bf2f(short s) {
  unsigned u = ((unsigned)(unsigned short)s) << 16;
  return __builtin_bit_cast(float, u);
}

// ---------------- prep ----------------
__global__ void prep_kernel(const float* __restrict__ ew0, const float* __restrict__ ew1,
                            const float* __restrict__ ew2, const float* __restrict__ ew3,
                            const float* __restrict__ nw0, const float* __restrict__ nw1,
                            const float* __restrict__ nw2, const float* __restrict__ nw3,
                            const int* __restrict__ eidx,
                            float* __restrict__ out, short* __restrict__ wbuf)
{
  int* wsi = (int*)wbuf;
  const int total = 1280000 + 50000 + WTOT;
  for (int i = blockIdx.x * blockDim.x + threadIdx.x; i < total; i += gridDim.x * blockDim.x) {
    if (i < 1280000) {
      out[OUT_IDX + i] = (float)eidx[i];
    } else if (i < 1330000) {
      wsi[CURS_I + (i - 1280000)] = 0;
    } else {
      int j = i - 1330000;
      short v;
      if (j < WPT)       { int n = j >> 7, k = j & 127; v = f2bf(ew0[(256 + k) * HD + n]); }        // We^T
      else if (j < EW1T) { int j2 = j - WPT, n = j2 >> 7, k = j2 & 127;
                           v = f2bf(ew0[((n < 128 ? 0 : 128) + k) * HD + (n & 127)]); }             // WP^T
      else if (j < EW2T) { int t2 = j - EW1T, n = t2 >> 7, k = t2 & 127; v = f2bf(ew1[k * HD + n]); }
      else if (j < EW3T) { int t2 = j - EW2T, n = t2 >> 7, k = t2 & 127; v = f2bf(ew2[k * HD + n]); }
      else if (j < NW0T) { int t2 = j - EW3T, n = t2 >> 7, k = t2 & 127; v = f2bf(ew3[k * HD + n]); }
      else if (j < NW1T) { int t2 = j - NW0T, n = t2 >> 8, k = t2 & 255; v = f2bf(nw0[k * HD + n]); }
      else if (j < NW2T) { int t2 = j - NW1T, n = t2 >> 7, k = t2 & 127; v = f2bf(nw1[k * HD + n]); }
      else if (j < NW3T) { int t2 = j - NW2T, n = t2 >> 7, k = t2 & 127; v = f2bf(nw2[k * HD + n]); }
      else               { int t2 = j - NW3T, n = t2 >> 7, k = t2 & 127; v = f2bf(nw3[k * HD + n]); }
      wbuf[j] = v;
    }
  }
}

// ---------------- CSR build ----------------
__global__ void hist_kernel(const int* __restrict__ eidx, short* __restrict__ wbuf) {
  int* counts = (int*)wbuf + CURS_I;
  int e = blockIdx.x * blockDim.x + threadIdx.x;
  if (e < N_EDGES_C) atomicAdd(&counts[eidx[N_EDGES_C + e]], 1);
}

__global__ void scan_kernel(short* __restrict__ wbuf) {
  int* wsi = (int*)wbuf;
  int* counts = wsi + CURS_I;
  int* offs = wsi + OFFS_I;
  __shared__ int tsum[1024];
  const int t = (int)threadIdx.x;
  const int per = (N_NODES_C + 1023) / 1024;
  const int base = t * per;
  const int lim = base + per < N_NODES_C ? base + per : N_NODES_C;
  int s = 0;
  for (int j = base; j < lim; ++j) s += counts[j];
  tsum[t] = s;
  __syncthreads();
  for (int off = 1; off < 1024; off <<= 1) {
    int v = tsum[t];
    int add = (t >= off) ? tsum[t - off] : 0;
    __syncthreads();
    tsum[t] = v + add;
    __syncthreads();
  }
  int run = (t == 0) ? 0 : tsum[t - 1];
  for (int j = base; j < lim; ++j) {
    int c = counts[j];
    offs[j] = run;
    counts[j] = run;
    run += c;
  }
  if (t == 1023) offs[N_NODES_C] = run;
}

__global__ void fill_kernel(const int* __restrict__ eidx, short* __restrict__ wbuf) {
  int* wsi = (int*)wbuf;
  int* cursor = wsi + CURS_I;
  int* elist = wsi + ELIST_I;
  int e = blockIdx.x * blockDim.x + threadIdx.x;
  if (e < N_EDGES_C) {
    int r = eidx[N_EDGES_C + e];
    int pos = atomicAdd(&cursor[r], 1);
    elist[pos] = e;
  }
}

// ---------------- shared MLP helpers ----------------
__device__ inline void zacc(f32x4 acc[4][2]) {
  #pragma unroll
  for (int i = 0; i < 4; ++i) {
    #pragma unroll
    for (int j = 0; j < 2; ++j) { f32x4 z = {0.f, 0.f, 0.f, 0.f}; acc[i][j] = z; }
  }
}

__device__ inline void mlp_ksteps(const short* __restrict__ Ab, const short* __restrict__ Wt,
                                  int Kw, int kglob0, f32x4 acc[4][2], int lr, int kg, int w)
{
  const short* ap = Ab + lr * 136 + kg * 8;
  const short* wp = Wt + (w * 32 + lr) * Kw + kglob0 + kg * 8;
  #pragma unroll
  for (int ks = 0; ks < 4; ++ks) {
    short8 a[4], b[2];
    #pragma unroll
    for (int mf = 0; mf < 4; ++mf) a[mf] = *(const short8*)(ap + mf * (16 * 136) + ks * 32);
    #pragma unroll
    for (int nf = 0; nf < 2; ++nf) b[nf] = *(const short8*)(wp + nf * 16 * Kw + ks * 32);
    #pragma unroll
    for (int mf = 0; mf < 4; ++mf) {
      #pragma unroll
      for (int nf = 0; nf < 2; ++nf)
        acc[mf][nf] = __builtin_amdgcn_mfma_f32_16x16x32_bf16(a[mf], b[nf], acc[mf][nf], 0, 0, 0);
    }
  }
}

__device__ inline void wb_bf16(short* __restrict__ dst, const float* __restrict__ bias,
                               f32x4 acc[4][2], int lr, int kg, int w, bool relu)
{
  #pragma unroll
  for (int nf = 0; nf < 2; ++nf) {
    const int col = w * 32 + nf * 16 + lr;
    const float bv = bias[col];
    #pragma unroll
    for (int mf = 0; mf < 4; ++mf) {
      #pragma unroll
      for (int r = 0; r < 4; ++r) {
        const int row = mf * 16 + kg * 4 + r;
        float v = acc[mf][nf][r] + bv;
        if (relu) v = fmaxf(v, 0.f);
        dst[row * 136 + col] = f2bf(v);
      }
    }
  }
}

__device__ inline void wb_plain(short* __restrict__ dst, f32x4 acc[4][2], int lr, int kg, int w)
{
  #pragma unroll
  for (int nf = 0; nf < 2; ++nf) {
    const int col = w * 32 + nf * 16 + lr;
    #pragma unroll
    for (int mf = 0; mf < 4; ++mf) {
      #pragma unroll
      for (int r = 0; r < 4; ++r) {
        const int row = mf * 16 + kg * 4 + r;
        dst[row * 136 + col] = f2bf(acc[mf][nf][r]);
      }
    }
  }
}

__device__ inline void wb_f32(float* __restrict__ dst, const float* __restrict__ bias,
                              f32x4 acc[4][2], int lr, int kg, int w)
{
  #pragma unroll
  for (int nf = 0; nf < 2; ++nf) {
    const int col = w * 32 + nf * 16 + lr;
    const float bv = bias[col];
    #pragma unroll
    for (int mf = 0; mf < 4; ++mf) {
      #pragma unroll
      for (int r = 0; r < 4; ++r) {
        const int row = mf * 16 + kg * 4 + r;
        dst[row * 132 + col] = acc[mf][nf][r] + bv;
      }
    }
  }
}

// ---------------- node_partial: P = nodef @ [Ws|Wr]  (bf16 out, no bias) ----------------
__global__ __launch_bounds__(256, 4) void node_partial_kernel(
    const float* __restrict__ nodef, short* __restrict__ wbuf)
{
  __shared__ short lds[2 * 64 * 136];
  short* B1 = lds;
  short* B2 = lds + 64 * 136;
  short* ptab = wbuf + PTAB_S;

  const int t = (int)threadIdx.x;
  const int lane = t & 63;
  const int w = t >> 6;
  const int lr = lane & 15;
  const int kg = lane >> 4;
  const int n0 = (int)blockIdx.x * 64;

  #pragma unroll
  for (int p = 0; p < 4; ++p) {
    int idx = p * 256 + t;
    int row = idx >> 4;
    int kc = idx & 15;
    int n = n0 + row;
    int ns = n < N_NODES_C ? n : 0;
    const float* src = nodef + (size_t)ns * HD + kc * 8;
    f32x4 v0 = *(const f32x4*)src;
    f32x4 v1 = *(const f32x4*)(src + 4);
    short8 sv;
    sv[0] = f2bf(v0[0]); sv[1] = f2bf(v0[1]); sv[2] = f2bf(v0[2]); sv[3] = f2bf(v0[3]);
    sv[4] = f2bf(v1[0]); sv[5] = f2bf(v1[1]); sv[6] = f2bf(v1[2]); sv[7] = f2bf(v1[3]);
    *(short8*)(B1 + row * 136 + kc * 8) = sv;
  }
  __syncthreads();

  f32x4 acc[4][2];
  #pragma unroll 1
  for (int h = 0; h < 2; ++h) {
    zacc(acc);
    mlp_ksteps(B1, wbuf + WPT + h * (128 * 128), 128, 0, acc, lr, kg, w);
    wb_plain(B2, acc, lr, kg, w);
    __syncthreads();
    #pragma unroll
    for (int p = 0; p < 4; ++p) {
      int idx = p * 256 + t;
      int row = idx >> 4;
      int kc = idx & 15;
      int n = n0 + row;
      if (n < N_NODES_C) {
        short8 sv = *(const short8*)(B2 + row * 136 + kc * 8);
        *(short8*)(ptab + (size_t)n * 256 + h * 128 + kc * 8) = sv;
      }
    }
    __syncthreads();
  }
}

// ---------------- edge kernel ----------------
__global__ __launch_bounds__(256, 4) void edge_kernel(
    const float* __restrict__ nodef, const float* __restrict__ eattr,
    const int* __restrict__ eidx,
    const float* __restrict__ b0, const float* __restrict__ b1,
    const float* __restrict__ b2, const float* __restrict__ b3,
    const float* __restrict__ gam, const float* __restrict__ bet,
    const short* __restrict__ wbuf, float* __restrict__ out)
{
  __shared__ short lds[2 * 64 * 136];
  short* B1 = lds;
  short* B2 = lds + 64 * 136;
  float* Hb = (float*)lds;
  const short* ptab = wbuf + PTAB_S;

  const int t = (int)threadIdx.x;
  const int lane = t & 63;
  const int w = t >> 6;
  const int lr = lane & 15;
  const int kg = lane >> 4;
  const int e0 = (int)blockIdx.x * 64;
  const int* senders = eidx;
  const int* recvs = eidx + N_EDGES_C;

  f32x4 acc[4][2];

  // ---- stage: eattr -> B1 (bf16), G = Ps[s]+Pr[r] -> B2 (bf16) ----
  #pragma unroll
  for (int p = 0; p < 4; ++p) {
    int idx = p * 256 + t;
    int row = idx >> 4;
    int kc = idx & 15;
    int e = e0 + row;
    const float* src = eattr + (size_t)e * HD + kc * 8;
    f32x4 v0 = *(const f32x4*)src;
    f32x4 v1 = *(const f32x4*)(src + 4);
    short8 sv;
    sv[0] = f2bf(v0[0]); sv[1] = f2bf(v0[1]); sv[2] = f2bf(v0[2]); sv[3] = f2bf(v0[3]);
    sv[4] = f2bf(v1[0]); sv[5] = f2bf(v1[1]); sv[6] = f2bf(v1[2]); sv[7] = f2bf(v1[3]);
    *(short8*)(B1 + row * 136 + kc * 8) = sv;

    int s = senders[e], r = recvs[e];
    short8 ps = *(const short8*)(ptab + (size_t)s * 256 + kc * 8);
    short8 pr = *(const short8*)(ptab + (size_t)r * 256 + 128 + kc * 8);
    short8 gv;
    #pragma unroll
    for (int x = 0; x < 8; ++x) gv[x] = f2bf(bf2f(ps[x]) + bf2f(pr[x]));
    *(short8*)(B2 + row * 136 + kc * 8) = gv;
  }
  __syncthreads();

  // ---- layer 0: Ep = eattr @ We^T; h0 = relu(Ep + G + b0) -> B2 ----
  zacc(acc);
  mlp_ksteps(B1, wbuf + EW0T, 128, 0, acc, lr, kg, w);
  #pragma unroll
  for (int nf = 0; nf < 2; ++nf) {
    const int col = w * 32 + nf * 16 + lr;
    const float bv = b0[col];
    #pragma unroll
    for (int mf = 0; mf < 4; ++mf) {
      #pragma unroll
      for (int r = 0; r < 4; ++r) {
        const int row = mf * 16 + kg * 4 + r;
        float v = acc[mf][nf][r] + bf2f(B2[row * 136 + col]) + bv;
        B2[row * 136 + col] = f2bf(fmaxf(v, 0.f));
      }
    }
  }
  __syncthreads();

  zacc(acc);
  mlp_ksteps(B2, wbuf + EW1T, 128, 0, acc, lr, kg, w);
  wb_bf16(B1, b1, acc, lr, kg, w, true);
  __syncthreads();

  zacc(acc);
  mlp_ksteps(B1, wbuf + EW2T, 128, 0, acc, lr, kg, w);
  wb_bf16(B2, b2, acc, lr, kg, w, true);
  __syncthreads();

  zacc(acc);
  mlp_ksteps(B2, wbuf + EW3T, 128, 0, acc, lr, kg, w);
  __syncthreads();
  wb_f32(Hb, b3, acc, lr, kg, w);
  __syncthreads();

  // ---- LayerNorm + residual store ----
  {
    const int row = t >> 2;
    const int q = t & 3;
    const int e = e0 + row;
    const float* hr = Hb + row * 132 + q * 32;
    float sum = 0.f, ss = 0.f;
    #pragma unroll
    for (int jj = 0; jj < 8; ++jj) {
      f32x4 v = *(const f32x4*)(hr + jj * 4);
      sum += v[0] + v[1] + v[2] + v[3];
      ss  += v[0] * v[0] + v[1] * v[1] + v[2] * v[2] + v[3] * v[3];
    }
    sum += __shfl_xor(sum, 1, 64); sum += __shfl_xor(sum, 2, 64);
    ss  += __shfl_xor(ss, 1, 64);  ss  += __shfl_xor(ss, 2, 64);
    const float mu = sum * (1.f / 128.f);
    const float var = ss * (1.f / 128.f) - mu * mu;
    const float rs = rsqrtf(var + 1e-5f);
    float* oute = out + OUT_EDGE + (size_t)e * HD + q * 32;
    const float* eap = eattr + (size_t)e * HD + q * 32;
    const float* gp = gam + q * 32;
    const float* bp = bet + q * 32;
    #pragma unroll
    for (int jj = 0; jj < 8; ++jj) {
      f32x4 v  = *(const f32x4*)(hr + jj * 4);
      f32x4 g4 = *(const f32x4*)(gp + jj * 4);
      f32x4 b4 = *(const f32x4*)(bp + jj * 4);
      f32x4 ea = *(const f32x4*)(eap + jj * 4);
      f32x4 res;
      #pragma unroll
      for (int x = 0; x < 4; ++x) res[x] = ea[x] + ((v[x] - mu) * rs * g4[x] + b4[x]);
      *(f32x4*)(oute + jj * 4) = res;
    }
  }
}

// ---------------- agg kernel: CSR gather-sum ----------------
__global__ __launch_bounds__(256, 8) void agg_kernel(
    const float* __restrict__ eattr, const short* __restrict__ wbuf,
    float* __restrict__ out)
{
  const int* wsi = (const int*)wbuf;
  const int* offs = wsi + OFFS_I;
  const int* ends = wsi + CURS_I;
  const int* elist = wsi + ELIST_I;

  const int t = (int)threadIdx.x;
  const int lane = t & 63;
  const int n = (int)blockIdx.x * 4 + (t >> 6);
  if (n >= N_NODES_C) return;

  const int start = offs[n];
  const int end = ends[n];
  f32x2 acc = {0.f, 0.f};
  const float* eo_base = out + OUT_EDGE + lane * 2;
  const float* ea_base = eattr + lane * 2;
  for (int j = start; j < end; ++j) {
    const int e = elist[j];
    f32x2 eo = *(const f32x2*)(eo_base + (size_t)e * HD);
    f32x2 ea = *(const f32x2*)(ea_base + (size_t)e * HD);
    acc[0] += eo[0] - ea[0];
    acc[1] += eo[1] - ea[1];
  }
  *(f32x2*)(out + OUT_NODE + (size_t)n * HD + lane * 2) = acc;
}

// ---------------- node kernel ----------------
__global__ __launch_bounds__(256, 4) void node_kernel(
    const float* __restrict__ nodef,
    const float* __restrict__ b0, const float* __restrict__ b1,
    const float* __restrict__ b2, const float* __restrict__ b3,
    const float* __restrict__ gam, const float* __restrict__ bet,
    const short* __restrict__ wbuf, float* __restrict__ out)
{
  __shared__ short lds[2 * 64 * 136];
  short* B1 = lds;
  short* B2 = lds + 64 * 136;
  float* Hb = (float*)lds;

  const int t = (int)threadIdx.x;
  const int lane = t & 63;
  const int w = t >> 6;
  const int lr = lane & 15;
  const int kg = lane >> 4;
  const int n0 = (int)blockIdx.x * 64;

  f32x4 acc[4][2];
  zacc(acc);

  #pragma unroll 1
  for (int c = 0; c < 2; ++c) {
    #pragma unroll
    for (int p = 0; p < 4; ++p) {
      int idx = p * 256 + t;
      int row = idx >> 4;
      int kc = idx & 15;
      int n = n0 + row;
      int ns = n < N_NODES_C ? n : 0;
      const float* src = (c == 0) ? (nodef + (size_t)ns * HD + kc * 8)
                                  : (out + OUT_NODE + (size_t)ns * HD + kc * 8);
      f32x4 v0 = *(const f32x4*)src;
      f32x4 v1 = *(const f32x4*)(src + 4);
      short8 sv;
      sv[0] = f2bf(v0[0]); sv[1] = f2bf(v0[1]); sv[2] = f2bf(v0[2]); sv[3] = f2bf(v0[3]);
      sv[4] = f2bf(v1[0]); sv[5] = f2bf(v1[1]); sv[6] = f2bf(v1[2]); sv[7] = f2bf(v1[3]);
      *(short8*)(B1 + row * 136 + kc * 8) = sv;
    }
    __syncthreads();
    mlp_ksteps(B1, wbuf + NW0T, 256, c * 128, acc, lr, kg, w);
    __syncthreads();
  }
  wb_bf16(B2, b0, acc, lr, kg, w, true);
  __syncthreads();

  zacc(acc);
  mlp_ksteps(B2, wbuf + NW1T, 128, 0, acc, lr, kg, w);
  wb_bf16(B1, b1, acc, lr, kg, w, true);
  __syncthreads();

  zacc(acc);
  mlp_ksteps(B1, wbuf + NW2T, 128, 0, acc, lr, kg, w);
  wb_bf16(B2, b2, acc, lr, kg, w, true);
  __syncthreads();

  zacc(acc);
  mlp_ksteps(B2, wbuf + NW3T, 128, 0, acc, lr, kg, w);
  __syncthreads();
  wb_f32(Hb, b3, acc, lr, kg, w);
  __syncthreads();

  {
    const int row = t >> 2;
    const int q = t & 3;
    const int n = n0 + row;
    const float* hr = Hb + row * 132 + q * 32;
    float sum = 0.f, ss = 0.f;
    #pragma unroll
    for (int jj = 0; jj < 8; ++jj) {
      f32x4 v = *(const f32x4*)(hr + jj * 4);
      sum += v[0] + v[1] + v[2] + v[3];
      ss  += v[0] * v[0] + v[1] * v[1] + v[2] * v[2] + v[3] * v[3];
    }
    sum += __shfl_xor(sum, 1, 64); sum += __shfl_xor(sum, 2, 64);
    ss  += __shfl_xor(ss, 1, 64);  ss  += __shfl_xor(ss, 2, 64);
    const float mu = sum * (1.f / 128.f);
    const float var = ss * (1.f / 128.f) - mu * mu;
    const float rs = rsqrtf(var + 1e-5f);
    if (n < N_NODES_C) {
      const float* nfp = nodef + (size_t)n * HD + q * 32;
      float* outp = out + OUT_NODE + (size_t)n * HD + q * 32;
      const float* gp = gam + q * 32;
      const float* bp = bet + q * 32;
      #pragma unroll
      for (int jj = 0; jj < 8; ++jj) {
        f32x4 v  = *(const f32x4*)(hr + jj * 4);
        f32x4 g4 = *(const f32x4*)(gp + jj * 4);
        f32x4 b4 = *(const f32x4*)(bp + jj * 4);
        f32x4 nf4 = *(const f32x4*)(nfp + jj * 4);
        f32x4 res;
        #pragma unroll
        for (int x = 0; x < 4; ++x) res[x] = nf4[x] + (v[x] - mu) * rs * g4[x] + b4[x];
        *(f32x4*)(outp + jj * 4) = res;
      }
    }
  }
}

extern "C" void kernel_launch(void* const* d_in, const int* in_sizes, int n_in,
                              void* d_out, int out_size, void* d_ws, size_t ws_size,
                              hipStream_t stream) {
  const float* nodef = (const float*)d_in[0];
  const float* eattr = (const float*)d_in[1];
  const int*   eidx  = (const int*)d_in[2];
  const float* e_w0 = (const float*)d_in[3];
  const float* e_b0 = (const float*)d_in[4];
  const float* e_w1 = (const float*)d_in[5];
  const float* e_b1 = (const float*)d_in[6];
  const float* e_w2 = (const float*)d_in[7];
  const float* e_b2 = (const float*)d_in[8];
  const float* e_w3 = (const float*)d_in[9];
  const float* e_b3 = (const float*)d_in[10];
  const float* e_g  = (const float*)d_in[11];
  const float* e_be = (const float*)d_in[12];
  const float* n_w0 = (const float*)d_in[13];
  const float* n_b0 = (const float*)d_in[14];
  const float* n_w1 = (const float*)d_in[15];
  const float* n_b1 = (const float*)d_in[16];
  const float* n_w2 = (const float*)d_in[17];
  const float* n_b2 = (const float*)d_in[18];
  const float* n_w3 = (const float*)d_in[19];
  const float* n_b3 = (const float*)d_in[20];
  const float* n_g  = (const float*)d_in[21];
  const float* n_be = (const float*)d_in[22];

  float* out = (float*)d_out;
  short* wbuf = (short*)d_ws;

  prep_kernel<<<2048, 256, 0, stream>>>(e_w0, e_w1, e_w2, e_w3, n_w0, n_w1, n_w2, n_w3,
                                        eidx, out, wbuf);
  node_partial_kernel<<<(N_NODES_C + 63) / 64, 256, 0, stream>>>(nodef, wbuf);
  hist_kernel<<<(N_EDGES_C + 255) / 256, 256, 0, stream>>>(eidx, wbuf);
  scan_kernel<<<1, 1024, 0, stream>>>(wbuf);
  fill_kernel<<<(N_EDGES_C + 255) / 256, 256, 0, stream>>>(eidx, wbuf);
  edge_kernel<<<N_EDGES_C / 64, 256, 0, stream>>>(nodef, eattr, eidx,
                                                  e_b0, e_b1, e_b2, e_b3, e_g, e_be,
                                                  wbuf, out);
  agg_kernel<<<(N_NODES_C + 3) / 4, 256, 0, stream>>>(eattr, wbuf, out);
  node_kernel<<<(N_NODES_C + 63) / 64, 256, 0, stream>>>(nodef,
                                                         n_b0, n_b1, n_b2, n_b3, n_g, n_be,
                                                         wbuf, out);
}